// Round 11
// baseline (177.927 us; speedup 1.0000x reference)
//
#include <hip/hip_runtime.h>

// CfC dose controller: B=4096 sequences, T=512 sequential steps.
// Layers (fan_in, hid): (4,9) (9,6) (6,1); gates ff1, ff2, t (t = ta+tb folded).
// f-space: gate value f = 1/(1 + 2^y), y pre-scaled dot
//   ff gates: y = -2*log2e*a  -> tanh(a) = 2f-1
//   t  gate : y = -  log2e*a  -> sigma(a) = f
// h_true = 2F-1 folded into consumer weights+biases.
//
// R11 = R10 split across 32 lanes/element (2048 waves = 2/SIMD, was 1/SIMD
// with every stall exposed). Lane (li,h): li=slot 0..15, h=half.
//   - state REPLICATED per half, half 1 stores PRE-ROTATED by 8:
//     lane (li,h) holds F[(li+8h)&15]  (8 = -8 mod 16 -> dir-free).
//   - dot split by rotation range: half h covers rotations 8h..8h+7 via the
//     SAME row_ror:1..7 immediates (pre-rotation makes ranges differ);
//     x cols {0,1}/{2,3} and bias split by half.
//   - partial exchange: v_permlane16_swap_b32 (VALU; __has_builtin-guarded,
//     ds_swizzle xor-16 fallback), output index RUNTIME-PROBED like R10's
//     dir probe -> pairing ambiguity cannot break semantics.
//   - commit: new F for stored neuron fetched with row_ror:8 (self-inverse).
//   - skew L0(i)|L1(i-1)|L2(i-2)|SIG(i-3), f-space folds, sigma schedule,
//     unroll-4 chunk prefetch: carried VERBATIM from R10 (passed, 9.8e-4).

#define LOG2E 1.44269504088896340736f
#define SMIN  0.001f

static constexpr int BATCH = 4096;
static constexpr int TLEN  = 512;

__device__ __forceinline__ float frcp(float x)  { return __builtin_amdgcn_rcpf(x); }
__device__ __forceinline__ float fexp2(float x) { return __builtin_amdgcn_exp2f(x); }
template<int CTRL>
__device__ __forceinline__ float dppf(float v) {
    return __int_as_float(__builtin_amdgcn_update_dpp(
        0, __float_as_int(v), CTRL, 0xF, 0xF, true));
}

#if defined(__has_builtin)
#if __has_builtin(__builtin_amdgcn_permlane16_swap)
#define HAVE_PL16 1
#endif
#endif

// cross-16 exchange: returns BOTH outputs; caller selects with probed mask
__device__ __forceinline__ void pswap(float v, float& o0, float& o1) {
#ifdef HAVE_PL16
    auto r = __builtin_amdgcn_permlane16_swap(__float_as_uint(v),
                                              __float_as_uint(v), false, false);
    o0 = __uint_as_float(r[0]);
    o1 = __uint_as_float(r[1]);
#else
    const float s = __int_as_float(
        __builtin_amdgcn_ds_swizzle(__float_as_int(v), 0x401F)); // xor lane^16
    o0 = s; o1 = s;
#endif
}

#define ROTSTEP(CTRL, R) { const float vr = dppf<CTRL>(F);      \
    a0 = fmaf(w0r[R], vr, a0); a1 = fmaf(w1r[R], vr, a1);       \
    a2 = fmaf(w2r[R], vr, a2); }

struct Params { const float* p[29]; float* out; };

__global__ __launch_bounds__(256, 2) void cfc_kernel(Params P) {
    const int tid = threadIdx.x;
    const int lie = tid & 31;                        // lane within element
    const int li  = lie & 15;                        // slot / accumulation neuron
    const int h   = lie >> 4;                        // half 0/1
    const int e   = ((blockIdx.x << 8) + tid) >> 5;  // batch element 0..4095

    // runtime probe of row_ror direction (only permutes the weight gather)
    const float got = dppf<0x121>((float)li);        // row_ror:1 on lane-id
    const int   dir = (((int)got) == ((li + 1) & 15)) ? 1 : -1;

    // runtime probe of permlane16_swap output pairing
    float p0, p1;
    pswap((float)(tid & 63), p0, p1);
    const bool useP0 = (((int)p0) == ((tid & 63) ^ 16));

    const int role = (li <= 8) ? 0 : (li <= 14 ? 1 : 2);   // accumulation neuron's layer
    const int jn   = (role == 0) ? li : (role == 1 ? li - 9 : 0);
    const int ns   = (li + 8 * h) & 15;                    // STORED neuron (dir-free)
    const int srole = (ns <= 8) ? 0 : (ns <= 14 ? 1 : 2);

    const float *Wf1, *Bf1, *Wf2, *Bf2, *Wa, *Ba, *Wb, *Bb, *Mk;
    int cat;
    if (role == 0)      { Wf1=P.p[1];  Bf1=P.p[2];  Wf2=P.p[3];  Bf2=P.p[4];
                          Wa=P.p[5];   Ba=P.p[6];   Wb=P.p[7];   Bb=P.p[8];  Mk=P.p[9];  cat=13; }
    else if (role == 1) { Wf1=P.p[10]; Bf1=P.p[11]; Wf2=P.p[12]; Bf2=P.p[13];
                          Wa=P.p[14];  Ba=P.p[15];  Wb=P.p[16];  Bb=P.p[17]; Mk=P.p[18]; cat=15; }
    else                { Wf1=P.p[19]; Bf1=P.p[20]; Wf2=P.p[21]; Bf2=P.p[22];
                          Wa=P.p[23];  Ba=P.p[24];  Wb=P.p[25];  Bb=P.p[26]; Mk=P.p[27]; cat=7;  }

    const float sc01 = -2.0f * LOG2E, sc2 = -LOG2E;

    // bias only in half 0 (added once after the exchange-sum)
    float b0 = 0.f, b1 = 0.f, b2 = 0.f;
    if (h == 0) {
        b0 = sc01 * Bf1[jn];
        b1 = sc01 * Bf2[jn];
        b2 = sc2  * (Ba[jn] + Bb[jn]);
    }

    // x-part weights: role 0 only; half h takes cat cols {2h, 2h+1}
    float xw0[2], xw1[2], xw2[2];
    #pragma unroll
    for (int c = 0; c < 2; ++c) {
        float a = 0.f, bq = 0.f, cq = 0.f;
        if (role == 0) {
            const int idx = jn * 13 + 2 * h + c;
            const float m = Mk[idx];
            a  = sc01 * Wf1[idx] * m;
            bq = sc01 * Wf2[idx] * m;
            cq = sc2  * (Wa[idx] + Wb[idx]);      // time gates dense
        }
        xw0[c] = a; xw1[c] = bq; xw2[c] = cq;
    }

    // rotation-ordered F-part weights: r'=0..7 -> slot k=(li+dir*(8h+r'))&15
    //   role 0: slots 0..8  -> cat col 4+k; role 1: slots 0..14 -> col k;
    //   role 2: slots 9..15 -> col k-9 (k<15), 6 (k==15)
    float w0r[8], w1r[8], w2r[8];
    #pragma unroll
    for (int r = 0; r < 8; ++r) {
        const int k = (li + dir * (8 * h + r)) & 15;
        int cc = -1;
        if (role == 0)      { if (k <= 8)  cc = 4 + k; }
        else if (role == 1) { if (k <= 14) cc = k; }
        else                { if (k >= 9)  cc = (k == 15) ? 6 : (k - 9); }
        float a = 0.f, bq = 0.f, cq = 0.f;
        if (cc >= 0) {
            const int idx = jn * cat + cc;
            const float m = Mk[idx];
            a  = sc01 * Wf1[idx] * m;
            bq = sc01 * Wf2[idx] * m;
            cq = sc2  * (Wa[idx] + Wb[idx]);
        }
        w0r[r] = a  + a;  b0 -= a;     // f-space fold: 2c*F, bias -= c
        w1r[r] = bq + bq; b1 -= bq;    // (each half subtracts its own terms)
        w2r[r] = cq + cq; b2 -= cq;
    }

    const float sig_scale = P.p[28][0];

    float F   = 0.5f;                  // stored slot's state (f-space)
    float sgv = 0.f;

    const float4* xp = reinterpret_cast<const float4*>(P.p[0]) + (size_t)e * TLEN;
    float* op = P.out + (size_t)e * TLEN;

    auto STEP = [&](const float4 xv, bool cA, bool cB, bool cC) {
        // sigma from lane's PRE-commit F (lane lie==15 holds F2(t-3))
        sgv = fmaf(sig_scale, frcp(1.0f + fexp2(fmaf(-2.0f * LOG2E, F, LOG2E))), SMIN);
        const float xc0 = h ? xv.z : xv.x;
        const float xc1 = h ? xv.w : xv.y;
        float a0 = fmaf(xw0[0], xc0, b0);
        float a1 = fmaf(xw1[0], xc0, b1);
        float a2 = fmaf(xw2[0], xc0, b2);
        a0 = fmaf(xw0[1], xc1, a0); a1 = fmaf(xw1[1], xc1, a1); a2 = fmaf(xw2[1], xc1, a2);
        a0 = fmaf(w0r[0], F, a0);   a1 = fmaf(w1r[0], F, a1);   a2 = fmaf(w2r[0], F, a2);
        ROTSTEP(0x121, 1) ROTSTEP(0x122, 2) ROTSTEP(0x123, 3) ROTSTEP(0x124, 4)
        ROTSTEP(0x125, 5) ROTSTEP(0x126, 6) ROTSTEP(0x127, 7)
        float u0, u1;
        pswap(a0, u0, u1); a0 += useP0 ? u0 : u1;   // full dot = partial + partner
        pswap(a1, u0, u1); a1 += useP0 ? u0 : u1;
        pswap(a2, u0, u1); a2 += useP0 ? u0 : u1;
        const float f0 = frcp(1.0f + fexp2(a0));    // ff1
        const float f1 = frcp(1.0f + fexp2(a1));    // ff2
        const float f2 = frcp(1.0f + fexp2(a2));    // t gate
        float Fn = fmaf(f2, f1 - f0, f0);           // neuron li's new F (both halves)
        const float Fr = dppf<0x128>(Fn);           // ror:8: stored neuron's new F
        Fn = h ? Fr : Fn;
        const bool cm = (srole == 0) ? cA : ((srole == 1) ? cB : cC);
        F = cm ? Fn : F;
    };

    // ---------------- prologue (fill 3-stage skew; no sigma yet) -------------
    STEP(xp[0], true, false, false);
    STEP(xp[1], true, true,  false);
    STEP(xp[2], true, true,  true);

    // ---------------- steady: iters t=3..510, unroll 4, chunk-ahead prefetch -
    float4 xs0 = xp[3], xs1 = xp[4], xs2 = xp[5], xs3 = xp[6];
    for (int m = 0; m < 127; ++m) {
        const int t = 3 + 4 * m;
        int pn = t + 4; if (pn > 508) pn = 508;          // clamp (no OOB)
        const float4 xn0 = xp[pn], xn1 = xp[pn + 1], xn2 = xp[pn + 2], xn3 = xp[pn + 3];
        STEP(xs0, true, true, true); const float s0 = sgv;   // sg(t-3)
        STEP(xs1, true, true, true); const float s1 = sgv;
        STEP(xs2, true, true, true); const float s2 = sgv;
        STEP(xs3, true, true, true); const float s3 = sgv;   // sg(t)
        if (lie == 15) { op[t - 3] = s0; op[t - 2] = s1; op[t - 1] = s2; op[t] = s3; }
        xs0 = xn0; xs1 = xn1; xs2 = xn2; xs3 = xn3;
    }
    // iter t=511 (xs3 = x[511])
    STEP(xs3, true, true, true);  const float s508 = sgv;

    // ---------------- epilogue (drain skew; x unused by committing roles) ----
    STEP(xs3, false, true,  true);  const float s509 = sgv;  // h1(511), h2(510)
    STEP(xs3, false, false, true);  const float s510 = sgv;  // h2(511)
    STEP(xs3, false, false, false); const float s511 = sgv;  // sg(511) only
    if (lie == 15) { op[508] = s508; op[509] = s509; op[510] = s510; op[511] = s511; }

    // ---------------- hx: half-0 lane li owns slot li -> coalesced -----------
    if (h == 0)
        P.out[(size_t)BATCH * TLEN + (size_t)e * 16 + li] = fmaf(2.0f, F, -1.0f);
}

extern "C" void kernel_launch(void* const* d_in, const int* in_sizes, int n_in,
                              void* d_out, int out_size, void* d_ws, size_t ws_size,
                              hipStream_t stream) {
    (void)in_sizes; (void)n_in; (void)out_size; (void)d_ws; (void)ws_size;
    Params P;
    for (int i = 0; i < 29; ++i) P.p[i] = (const float*)d_in[i];
    P.out = (float*)d_out;
    // 4096 elements, 32 lanes each: 512 blocks x 256 threads (8 elems/block)
    hipLaunchKernelGGL(cfc_kernel, dim3(BATCH / 8), dim3(256), 0, stream, P);
}

// Round 12
// 98.286 us; speedup vs baseline: 1.8103x; 1.8103x over previous
//
#include <hip/hip_runtime.h>

// CfC dose controller: B=4096 sequences, T=512 sequential steps.
// Layers (fan_in, hid): (4,9) (9,6) (6,1); gates ff1, ff2, t (t = ta+tb folded).
// f-space: gate value f = 1/(1 + 2^y), y pre-scaled dot
//   ff gates: y = -2*log2e*a  -> tanh(a) = 2f-1
//   t  gate : y = -  log2e*a  -> sigma(a) = f
// h_true = 2F-1 folded into consumer weights+biases.
//
// R12 = R10 (verbatim; 92.6us, best) + sigma OFF-LOADED from the recurrent
// loop. Lane 15 stores raw pre-commit F (same schedule/slots); a second
// trivially-parallel kernel transforms the B*T block in place with the
// IDENTICAL instruction sequence (fmaf/exp2/rcp/fmaf -> bit-identical).
// Saves 4 inst incl 2 of 8 transcendentals per step on the critical loop.
// R11 lesson (92.6 -> 178us): 32-lane split bloated codegen ~2.5x (VGPR 80->40,
// remat/spill copies count as VALU); revert, keep the 16-lane mapping.

#define LOG2E 1.44269504088896340736f
#define SMIN  0.001f

static constexpr int BATCH = 4096;
static constexpr int TLEN  = 512;

__device__ __forceinline__ float frcp(float x)  { return __builtin_amdgcn_rcpf(x); }
__device__ __forceinline__ float fexp2(float x) { return __builtin_amdgcn_exp2f(x); }
template<int CTRL>
__device__ __forceinline__ float dppf(float v) {
    return __int_as_float(__builtin_amdgcn_update_dpp(
        0, __float_as_int(v), CTRL, 0xF, 0xF, true));
}

// one rotation step: vr = F rotated by R within the 16-lane row; 3 fmacs share it
#define ROTSTEP(CTRL, R) { const float vr = dppf<CTRL>(F);                               \
    if ((R) & 1) { a0b = fmaf(w0r[R], vr, a0b); a1b = fmaf(w1r[R], vr, a1b);             \
                   a2b = fmaf(w2r[R], vr, a2b); }                                        \
    else         { a0  = fmaf(w0r[R], vr, a0 ); a1  = fmaf(w1r[R], vr, a1 );             \
                   a2  = fmaf(w2r[R], vr, a2 ); } }

struct Params { const float* p[29]; float* out; };

__global__ __launch_bounds__(256, 1) void cfc_kernel(Params P) {
    const int tid = threadIdx.x;
    const int li  = tid & 15;                        // lane within element group
    const int e   = (blockIdx.x << 4) + (tid >> 4);  // batch element 0..4095

    // runtime probe of row_ror direction (only permutes the weight gather)
    const float got = dppf<0x121>((float)li);        // row_ror:1 on lane-id
    const int   dir = (((int)got) == ((li + 1) & 15)) ? 1 : -1;

    const int role = (li <= 8) ? 0 : (li <= 14 ? 1 : 2);
    const int jn   = (role == 0) ? li : (role == 1 ? li - 9 : 0);

    const float *Wf1, *Bf1, *Wf2, *Bf2, *Wa, *Ba, *Wb, *Bb, *Mk;
    int cat;
    if (role == 0)      { Wf1=P.p[1];  Bf1=P.p[2];  Wf2=P.p[3];  Bf2=P.p[4];
                          Wa=P.p[5];   Ba=P.p[6];   Wb=P.p[7];   Bb=P.p[8];  Mk=P.p[9];  cat=13; }
    else if (role == 1) { Wf1=P.p[10]; Bf1=P.p[11]; Wf2=P.p[12]; Bf2=P.p[13];
                          Wa=P.p[14];  Ba=P.p[15];  Wb=P.p[16];  Bb=P.p[17]; Mk=P.p[18]; cat=15; }
    else                { Wf1=P.p[19]; Bf1=P.p[20]; Wf2=P.p[21]; Bf2=P.p[22];
                          Wa=P.p[23];  Ba=P.p[24];  Wb=P.p[25];  Bb=P.p[26]; Mk=P.p[27]; cat=7;  }

    const float sc01 = -2.0f * LOG2E, sc2 = -LOG2E;
    float b0 = sc01 * Bf1[jn], b1 = sc01 * Bf2[jn], b2 = sc2 * (Ba[jn] + Bb[jn]);

    // x-part weights (role 0 only; zero elsewhere)
    float xw0[4], xw1[4], xw2[4];
    #pragma unroll
    for (int c = 0; c < 4; ++c) {
        float a = 0.f, bq = 0.f, cq = 0.f;
        if (role == 0) {
            const int idx = jn * 13 + c;
            const float m = Mk[idx];
            a  = sc01 * Wf1[idx] * m;
            bq = sc01 * Wf2[idx] * m;
            cq = sc2  * (Wa[idx] + Wb[idx]);
        }
        xw0[c] = a; xw1[c] = bq; xw2[c] = cq;
    }

    // rotation-ordered F-part weights: slot k = (li + dir*r) & 15
    //   role 0: slots 0..8  -> cat col 4+k   (L0 recurrent block)
    //   role 1: slots 0..14 -> cat col k     (L1: h0 then h1)
    //   role 2: slots 9..15 -> cat col k-9 (k<15), 6 (k==15)
    float w0r[16], w1r[16], w2r[16];
    #pragma unroll
    for (int r = 0; r < 16; ++r) {
        const int k = (li + dir * r) & 15;
        int cc = -1;
        if (role == 0)      { if (k <= 8)  cc = 4 + k; }
        else if (role == 1) { if (k <= 14) cc = k; }
        else                { if (k >= 9)  cc = (k == 15) ? 6 : (k - 9); }
        float a = 0.f, bq = 0.f, cq = 0.f;
        if (cc >= 0) {
            const int idx = jn * cat + cc;
            const float m = Mk[idx];
            a  = sc01 * Wf1[idx] * m;
            bq = sc01 * Wf2[idx] * m;
            cq = sc2  * (Wa[idx] + Wb[idx]);
        }
        w0r[r] = a  + a;  b0 -= a;     // f-space fold: 2c*F, bias -= c
        w1r[r] = bq + bq; b1 -= bq;
        w2r[r] = cq + cq; b2 -= cq;
    }

    float F = 0.5f;                    // own state slot (f-space; h=0 <=> 0.5)

    const float4* xp = reinterpret_cast<const float4*>(P.p[0]) + (size_t)e * TLEN;
    float* op = P.out + (size_t)e * TLEN;

    auto STEP = [&](const float4 xv, bool cA, bool cB, bool cC) {
        float a0 = b0, a1 = b1, a2 = b2;
        float a0b = xw0[0] * xv.x, a1b = xw1[0] * xv.x, a2b = xw2[0] * xv.x;
        a0b = fmaf(xw0[1], xv.y, a0b); a1b = fmaf(xw1[1], xv.y, a1b); a2b = fmaf(xw2[1], xv.y, a2b);
        a0b = fmaf(xw0[2], xv.z, a0b); a1b = fmaf(xw1[2], xv.z, a1b); a2b = fmaf(xw2[2], xv.z, a2b);
        a0b = fmaf(xw0[3], xv.w, a0b); a1b = fmaf(xw1[3], xv.w, a1b); a2b = fmaf(xw2[3], xv.w, a2b);
        a0 = fmaf(w0r[0], F, a0); a1 = fmaf(w1r[0], F, a1); a2 = fmaf(w2r[0], F, a2); // r=0 self
        ROTSTEP(0x121, 1)  ROTSTEP(0x122, 2)  ROTSTEP(0x123, 3)  ROTSTEP(0x124, 4)
        ROTSTEP(0x125, 5)  ROTSTEP(0x126, 6)  ROTSTEP(0x127, 7)  ROTSTEP(0x128, 8)
        ROTSTEP(0x129, 9)  ROTSTEP(0x12A, 10) ROTSTEP(0x12B, 11) ROTSTEP(0x12C, 12)
        ROTSTEP(0x12D, 13) ROTSTEP(0x12E, 14) ROTSTEP(0x12F, 15)
        const float y0 = a0 + a0b, y1 = a1 + a1b, y2 = a2 + a2b;
        const float f0 = frcp(1.0f + fexp2(y0));   // ff1
        const float f1 = frcp(1.0f + fexp2(y1));   // ff2
        const float f2 = frcp(1.0f + fexp2(y2));   // t gate
        const float Fn = fmaf(f2, f1 - f0, f0);
        const bool cm = (role == 0) ? cA : ((role == 1) ? cB : cC);
        F = cm ? Fn : F;
    };

    // ---------------- prologue (fill 3-stage skew; no sigma yet) -------------
    STEP(xp[0], true, false, false);
    STEP(xp[1], true, true,  false);
    STEP(xp[2], true, true,  true);

    // ---------------- steady: iters t=3..510, unroll 4, chunk-ahead prefetch -
    // sigma capture: raw pre-commit F (lane 15 = F2); transform done by
    // sig_kernel afterwards. Capture-before-STEP == R10's sgv-inside-STEP.
    float4 xs0 = xp[3], xs1 = xp[4], xs2 = xp[5], xs3 = xp[6];
    for (int m = 0; m < 127; ++m) {
        const int t = 3 + 4 * m;
        int pn = t + 4; if (pn > 508) pn = 508;          // clamp (no OOB)
        const float4 xn0 = xp[pn], xn1 = xp[pn + 1], xn2 = xp[pn + 2], xn3 = xp[pn + 3];
        const float s0 = F; STEP(xs0, true, true, true);   // raw sg-src(t-3)
        const float s1 = F; STEP(xs1, true, true, true);
        const float s2 = F; STEP(xs2, true, true, true);
        const float s3 = F; STEP(xs3, true, true, true);   // raw sg-src(t)
        if (li == 15) { op[t - 3] = s0; op[t - 2] = s1; op[t - 1] = s2; op[t] = s3; }
        xs0 = xn0; xs1 = xn1; xs2 = xn2; xs3 = xn3;
    }
    // iter t=511 (xs3 = x[511])
    const float s508 = F; STEP(xs3, true, true, true);

    // ---------------- epilogue (drain skew; x unused by committing roles) ----
    const float s509 = F; STEP(xs3, false, true,  true);  // h1(511), h2(510)
    const float s510 = F; STEP(xs3, false, false, true);  // h2(511)
    const float s511 = F;                                 // sg(511) source
    if (li == 15) { op[508] = s508; op[509] = s509; op[510] = s510; op[511] = s511; }

    // ---------------- hx: each lane owns exactly its slot -> coalesced -------
    P.out[(size_t)BATCH * TLEN + (size_t)e * 16 + li] = fmaf(2.0f, F, -1.0f);
}

// in-place sigma transform over the B*T block: sigma = sc*sigmoid(2F-1)+SMIN
// (identical instruction sequence to R10's in-loop version -> bit-identical)
__global__ __launch_bounds__(256) void sig_kernel(float* out, const float* sp) {
    const float sc = sp[0];
    const int i = (blockIdx.x << 8) + threadIdx.x;     // one float4 per thread
    float4 v = reinterpret_cast<float4*>(out)[i];
    v.x = fmaf(sc, frcp(1.0f + fexp2(fmaf(-2.0f * LOG2E, v.x, LOG2E))), SMIN);
    v.y = fmaf(sc, frcp(1.0f + fexp2(fmaf(-2.0f * LOG2E, v.y, LOG2E))), SMIN);
    v.z = fmaf(sc, frcp(1.0f + fexp2(fmaf(-2.0f * LOG2E, v.z, LOG2E))), SMIN);
    v.w = fmaf(sc, frcp(1.0f + fexp2(fmaf(-2.0f * LOG2E, v.w, LOG2E))), SMIN);
    reinterpret_cast<float4*>(out)[i] = v;
}

extern "C" void kernel_launch(void* const* d_in, const int* in_sizes, int n_in,
                              void* d_out, int out_size, void* d_ws, size_t ws_size,
                              hipStream_t stream) {
    (void)in_sizes; (void)n_in; (void)out_size; (void)d_ws; (void)ws_size;
    Params P;
    for (int i = 0; i < 29; ++i) P.p[i] = (const float*)d_in[i];
    P.out = (float*)d_out;
    // 4096 elements, 16 lanes each: 256 blocks x 256 threads (4 elems/wave)
    hipLaunchKernelGGL(cfc_kernel, dim3(BATCH / 16), dim3(256), 0, stream, P);
    // sigma transform: B*T floats = 524288 float4 = 2048 blocks x 256
    hipLaunchKernelGGL(sig_kernel, dim3((BATCH * TLEN) / 1024), dim3(256), 0, stream,
                       (float*)d_out, (const float*)d_in[28]);
}